// Round 3
// baseline (250.973 us; speedup 1.0000x reference)
//
#include <hip/hip_runtime.h>

// LIF scan, T=8, N=4M fp32 neurons. Memory-bound: 256 MiB traffic, roofline
// ~43 us @ 6.3 TB/s. R1/R2 lesson: the compiler sinks batched loads into the
// consume loop (VGPR 24/36), interleaving them with stores; each load-use then
// needs vmcnt(0) which drains store-acks too -> fully serialized waves at
// ~2.2 TB/s. R3: inline-asm load batch (8x global_load_dwordx4, 8 KiB in
// flight/wave) + single waitcnt tied to all results via "+v" operands, all
// stores strictly after all loads.

#define LIF_THRESH 0.5f
#define LIF_BETA   0.25f
#define LIF_T      8

typedef float v4f __attribute__((ext_vector_type(4)));

__device__ __forceinline__ float lif_step(float& m, float xv) {
    m = m * LIF_BETA + xv;
    float s = (m >= LIF_THRESH) ? 1.f : 0.f;
    m = (m >= LIF_THRESH) ? 0.f : m;
    return s;
}

__global__ __launch_bounds__(256) void lif_kernel(const v4f* __restrict__ x,
                                                  v4f* __restrict__ out,
                                                  int n4) {
    int i = blockIdx.x * 256 + threadIdx.x;
    if (i >= n4) return;

    const v4f* p0 = x + i;
    const v4f* p1 = p0 + (size_t)n4;
    const v4f* p2 = p1 + (size_t)n4;
    const v4f* p3 = p2 + (size_t)n4;
    const v4f* p4 = p3 + (size_t)n4;
    const v4f* p5 = p4 + (size_t)n4;
    const v4f* p6 = p5 + (size_t)n4;
    const v4f* p7 = p6 + (size_t)n4;

    // 8 loads issued back-to-back; volatile asm is mutually ordered and cannot
    // be sunk by the compiler. 8 KiB outstanding per wave.
    v4f x0, x1, x2, x3, x4, x5, x6, x7;
    asm volatile("global_load_dwordx4 %0, %1, off" : "=v"(x0) : "v"(p0) : "memory");
    asm volatile("global_load_dwordx4 %0, %1, off" : "=v"(x1) : "v"(p1) : "memory");
    asm volatile("global_load_dwordx4 %0, %1, off" : "=v"(x2) : "v"(p2) : "memory");
    asm volatile("global_load_dwordx4 %0, %1, off" : "=v"(x3) : "v"(p3) : "memory");
    asm volatile("global_load_dwordx4 %0, %1, off" : "=v"(x4) : "v"(p4) : "memory");
    asm volatile("global_load_dwordx4 %0, %1, off" : "=v"(x5) : "v"(p5) : "memory");
    asm volatile("global_load_dwordx4 %0, %1, off" : "=v"(x6) : "v"(p6) : "memory");
    asm volatile("global_load_dwordx4 %0, %1, off" : "=v"(x7) : "v"(p7) : "memory");
    // Single drain; "+v" ties every result so no consumer can be scheduled
    // before this point.
    asm volatile("s_waitcnt vmcnt(0)"
                 : "+v"(x0), "+v"(x1), "+v"(x2), "+v"(x3),
                   "+v"(x4), "+v"(x5), "+v"(x6), "+v"(x7)
                 :
                 : "memory");

    float m0 = 0.f, m1 = 0.f, m2 = 0.f, m3 = 0.f;
    v4f s0, s1, s2, s3, s4, s5, s6, s7;
#define STEP(S, XV)                    \
    S.x = lif_step(m0, XV.x);          \
    S.y = lif_step(m1, XV.y);          \
    S.z = lif_step(m2, XV.z);          \
    S.w = lif_step(m3, XV.w);
    STEP(s0, x0) STEP(s1, x1) STEP(s2, x2) STEP(s3, x3)
    STEP(s4, x4) STEP(s5, x5) STEP(s6, x6) STEP(s7, x7)
#undef STEP

    // All stores after all loads: no load ever waits behind a store ack.
    // Nontemporal: output is write-once, keep L3 for the input stream.
    v4f* q = out + i;
    __builtin_nontemporal_store(s0, q); q += n4;
    __builtin_nontemporal_store(s1, q); q += n4;
    __builtin_nontemporal_store(s2, q); q += n4;
    __builtin_nontemporal_store(s3, q); q += n4;
    __builtin_nontemporal_store(s4, q); q += n4;
    __builtin_nontemporal_store(s5, q); q += n4;
    __builtin_nontemporal_store(s6, q); q += n4;
    __builtin_nontemporal_store(s7, q);
}

extern "C" void kernel_launch(void* const* d_in, const int* in_sizes, int n_in,
                              void* d_out, int out_size, void* d_ws, size_t ws_size,
                              hipStream_t stream) {
    const v4f* x = (const v4f*)d_in[0];
    v4f* out = (v4f*)d_out;

    long long total = in_sizes[0];
    int n = (int)(total / LIF_T);   // 4,194,304 floats per timestep
    int n4 = n / 4;                 // 1,048,576 float4 per timestep

    dim3 block(256);
    dim3 grid((n4 + 255) / 256);    // 4096 blocks
    lif_kernel<<<grid, block, 0, stream>>>(x, out, n4);
}

// Round 4
// 241.137 us; speedup vs baseline: 1.0408x; 1.0408x over previous
//
#include <hip/hip_runtime.h>

// LIF scan, T=8, N=4M fp32. Memory-bound, roofline ~43 us @ 6.3 TB/s.
// R1-R3 all plateau at 2.1-2.4 TB/s regardless of per-wave load structure ->
// systemic limiter. Theory: per-CU footprint sprawl (16 blocks x 16 streams
// strided by 2^24 B -> TLB/channel hot-spotting). R4: block-contiguous
// chunking (1024 blocks x 4 chunks), depth-2 asm software pipeline with
// vmcnt(8)/vmcnt(16) waits (never wait on store acks), launch_bounds(256,1)
// for full VGPR budget.

#define LIF_THRESH 0.5f
#define LIF_BETA   0.25f
#define LIF_T      8
#define BLOCK      256
#define JITER      4

typedef float v4f __attribute__((ext_vector_type(4)));

__device__ __forceinline__ float lif_step(float& m, float xv) {
    m = m * LIF_BETA + xv;
    float s = (m >= LIF_THRESH) ? 1.f : 0.f;
    m = (m >= LIF_THRESH) ? 0.f : m;
    return s;
}

// Issue 8 plane-strided loads back-to-back (volatile asm: ordered, un-sinkable).
#define ISSUE8(r0, r1, r2, r3, r4, r5, r6, r7, COL)                                            \
    {                                                                                          \
        const v4f* _p = x + (size_t)(COL);                                                     \
        asm volatile("global_load_dwordx4 %0, %1, off" : "=v"(r0) : "v"(_p) : "memory");       \
        _p += n4;                                                                              \
        asm volatile("global_load_dwordx4 %0, %1, off" : "=v"(r1) : "v"(_p) : "memory");       \
        _p += n4;                                                                              \
        asm volatile("global_load_dwordx4 %0, %1, off" : "=v"(r2) : "v"(_p) : "memory");       \
        _p += n4;                                                                              \
        asm volatile("global_load_dwordx4 %0, %1, off" : "=v"(r3) : "v"(_p) : "memory");       \
        _p += n4;                                                                              \
        asm volatile("global_load_dwordx4 %0, %1, off" : "=v"(r4) : "v"(_p) : "memory");       \
        _p += n4;                                                                              \
        asm volatile("global_load_dwordx4 %0, %1, off" : "=v"(r5) : "v"(_p) : "memory");       \
        _p += n4;                                                                              \
        asm volatile("global_load_dwordx4 %0, %1, off" : "=v"(r6) : "v"(_p) : "memory");       \
        _p += n4;                                                                              \
        asm volatile("global_load_dwordx4 %0, %1, off" : "=v"(r7) : "v"(_p) : "memory");       \
    }

// Wait until at most CNT vector-memory ops outstanding; ties the 8 results so
// no consumer can be scheduled before this point.
#define WAIT8(r0, r1, r2, r3, r4, r5, r6, r7, CNT)                                             \
    asm volatile("s_waitcnt vmcnt(" #CNT ")"                                                   \
                 : "+v"(r0), "+v"(r1), "+v"(r2), "+v"(r3),                                     \
                   "+v"(r4), "+v"(r5), "+v"(r6), "+v"(r7)                                      \
                 :                                                                             \
                 : "memory");

// Full LIF scan over 8 planes for one column + 8 nontemporal stores.
#define COMPUTE_STORE(r0, r1, r2, r3, r4, r5, r6, r7, COL)                                     \
    {                                                                                          \
        float m0 = 0.f, m1 = 0.f, m2 = 0.f, m3 = 0.f;                                          \
        v4f s;                                                                                 \
        v4f* _q = out + (size_t)(COL);                                                         \
        s.x = lif_step(m0, r0.x); s.y = lif_step(m1, r0.y);                                    \
        s.z = lif_step(m2, r0.z); s.w = lif_step(m3, r0.w);                                    \
        __builtin_nontemporal_store(s, _q); _q += n4;                                          \
        s.x = lif_step(m0, r1.x); s.y = lif_step(m1, r1.y);                                    \
        s.z = lif_step(m2, r1.z); s.w = lif_step(m3, r1.w);                                    \
        __builtin_nontemporal_store(s, _q); _q += n4;                                          \
        s.x = lif_step(m0, r2.x); s.y = lif_step(m1, r2.y);                                    \
        s.z = lif_step(m2, r2.z); s.w = lif_step(m3, r2.w);                                    \
        __builtin_nontemporal_store(s, _q); _q += n4;                                          \
        s.x = lif_step(m0, r3.x); s.y = lif_step(m1, r3.y);                                    \
        s.z = lif_step(m2, r3.z); s.w = lif_step(m3, r3.w);                                    \
        __builtin_nontemporal_store(s, _q); _q += n4;                                          \
        s.x = lif_step(m0, r4.x); s.y = lif_step(m1, r4.y);                                    \
        s.z = lif_step(m2, r4.z); s.w = lif_step(m3, r4.w);                                    \
        __builtin_nontemporal_store(s, _q); _q += n4;                                          \
        s.x = lif_step(m0, r5.x); s.y = lif_step(m1, r5.y);                                    \
        s.z = lif_step(m2, r5.z); s.w = lif_step(m3, r5.w);                                    \
        __builtin_nontemporal_store(s, _q); _q += n4;                                          \
        s.x = lif_step(m0, r6.x); s.y = lif_step(m1, r6.y);                                    \
        s.z = lif_step(m2, r6.z); s.w = lif_step(m3, r6.w);                                    \
        __builtin_nontemporal_store(s, _q); _q += n4;                                          \
        s.x = lif_step(m0, r7.x); s.y = lif_step(m1, r7.y);                                    \
        s.z = lif_step(m2, r7.z); s.w = lif_step(m3, r7.w);                                    \
        __builtin_nontemporal_store(s, _q);                                                    \
    }

__global__ __launch_bounds__(BLOCK, 1) void lif_kernel(const v4f* __restrict__ x,
                                                       v4f* __restrict__ out,
                                                       int n4) {
    // Block b owns the contiguous column range [b*BLOCK*JITER, (b+1)*BLOCK*JITER):
    // per-CU instantaneous footprint = resident blocks x 16 streams, each walked
    // contiguously -> narrow TLB/channel working set.
    const int c0 = blockIdx.x * (BLOCK * JITER) + threadIdx.x;
    const int c1 = c0 + BLOCK;
    const int c2 = c1 + BLOCK;
    const int c3 = c2 + BLOCK;

    v4f a0, a1, a2, a3, a4, a5, a6, a7;   // pipeline buffer A
    v4f b0, b1, b2, b3, b4, b5, b6, b7;   // pipeline buffer B

    ISSUE8(a0, a1, a2, a3, a4, a5, a6, a7, c0)   // 8 in flight
    ISSUE8(b0, b1, b2, b3, b4, b5, b6, b7, c1)   // 16 in flight

    // chunk 0: wait A done (B's 8 loads may remain outstanding)
    WAIT8(a0, a1, a2, a3, a4, a5, a6, a7, 8)
    COMPUTE_STORE(a0, a1, a2, a3, a4, a5, a6, a7, c0)      // +8 stores
    ISSUE8(a0, a1, a2, a3, a4, a5, a6, a7, c2)             // +8 loads

    // chunk 1: younger ops = stores(c0) + loads(c2) = 16 -> B done at vmcnt(16)
    WAIT8(b0, b1, b2, b3, b4, b5, b6, b7, 16)
    COMPUTE_STORE(b0, b1, b2, b3, b4, b5, b6, b7, c1)
    ISSUE8(b0, b1, b2, b3, b4, b5, b6, b7, c3)

    // chunk 2: younger = stores(c1) + loads(c3) = 16 -> A done at vmcnt(16)
    WAIT8(a0, a1, a2, a3, a4, a5, a6, a7, 16)
    COMPUTE_STORE(a0, a1, a2, a3, a4, a5, a6, a7, c2)

    // chunk 3: younger = stores(c2) = 8 -> B done at vmcnt(8)
    WAIT8(b0, b1, b2, b3, b4, b5, b6, b7, 8)
    COMPUTE_STORE(b0, b1, b2, b3, b4, b5, b6, b7, c3)
}

extern "C" void kernel_launch(void* const* d_in, const int* in_sizes, int n_in,
                              void* d_out, int out_size, void* d_ws, size_t ws_size,
                              hipStream_t stream) {
    const v4f* x = (const v4f*)d_in[0];
    v4f* out = (v4f*)d_out;

    long long total = in_sizes[0];
    int n = (int)(total / LIF_T);   // 4,194,304 floats per timestep
    int n4 = n / 4;                 // 1,048,576 float4 columns per timestep

    // 1,048,576 / (256*4) = 1024 blocks, each owning a contiguous 16 KiB/plane.
    dim3 block(BLOCK);
    dim3 grid(n4 / (BLOCK * JITER));
    lif_kernel<<<grid, block, 0, stream>>>(x, out, n4);
}

// Round 5
// 230.127 us; speedup vs baseline: 1.0906x; 1.0478x over previous
//
#include <hip/hip_runtime.h>

// LIF scan, T=8, N=4M fp32. 256 MiB logical traffic, roofline ~43 us @ 6.3 TB/s.
// R1-R4: four different structures / occupancies 30-66% all plateau at
// 2.1-2.4 TB/s HBM (~4.9 B/cyc/CU vs copy's 10.2) -> per-CU service-rate cap,
// not latency/MLP/occupancy. R5 single-variable probe: nontemporal LOADS
// (streaming policy, skip L2/L3 allocate) on top of R1's simple structure.

#define LIF_THRESH 0.5f
#define LIF_BETA   0.25f
#define LIF_T      8

typedef float v4f __attribute__((ext_vector_type(4)));

__global__ __launch_bounds__(256) void lif_kernel(const v4f* __restrict__ x,
                                                  v4f* __restrict__ out,
                                                  int n4) {
    int i = blockIdx.x * 256 + threadIdx.x;
    if (i >= n4) return;

    // Streaming loads: this data is read exactly once; nt policy avoids
    // allocate/evict churn in L1/L2/L3 on the read path.
    v4f xv[LIF_T];
#pragma unroll
    for (int t = 0; t < LIF_T; ++t) {
        xv[t] = __builtin_nontemporal_load(&x[(size_t)t * n4 + i]);
    }

    float m0 = 0.f, m1 = 0.f, m2 = 0.f, m3 = 0.f;
#pragma unroll
    for (int t = 0; t < LIF_T; ++t) {
        v4f xt = xv[t];
        m0 = m0 * LIF_BETA + xt.x;
        m1 = m1 * LIF_BETA + xt.y;
        m2 = m2 * LIF_BETA + xt.z;
        m3 = m3 * LIF_BETA + xt.w;

        v4f s;
        s.x = (m0 >= LIF_THRESH) ? 1.f : 0.f;
        s.y = (m1 >= LIF_THRESH) ? 1.f : 0.f;
        s.z = (m2 >= LIF_THRESH) ? 1.f : 0.f;
        s.w = (m3 >= LIF_THRESH) ? 1.f : 0.f;

        m0 = (m0 >= LIF_THRESH) ? 0.f : m0;
        m1 = (m1 >= LIF_THRESH) ? 0.f : m1;
        m2 = (m2 >= LIF_THRESH) ? 0.f : m2;
        m3 = (m3 >= LIF_THRESH) ? 0.f : m3;

        // Output is write-once: keep nt stores.
        __builtin_nontemporal_store(s, &out[(size_t)t * n4 + i]);
    }
}

extern "C" void kernel_launch(void* const* d_in, const int* in_sizes, int n_in,
                              void* d_out, int out_size, void* d_ws, size_t ws_size,
                              hipStream_t stream) {
    const v4f* x = (const v4f*)d_in[0];
    v4f* out = (v4f*)d_out;

    long long total = in_sizes[0];
    int n = (int)(total / LIF_T);   // 4,194,304 floats per timestep
    int n4 = n / 4;                 // 1,048,576 float4 per timestep

    dim3 block(256);
    dim3 grid((n4 + 255) / 256);    // 4096 blocks
    lif_kernel<<<grid, block, 0, stream>>>(x, out, n4);
}